// Round 2
// baseline (375.509 us; speedup 1.0000x reference)
//
#include <hip/hip_runtime.h>

#define S_LEN 4096
#define DIM   256
#define QBLK  64
#define KVBLK 64

typedef __attribute__((ext_vector_type(4))) float f32x4;
typedef __attribute__((ext_vector_type(8))) short bf16x8;
typedef __attribute__((ext_vector_type(4))) unsigned short u16x4;

// fp32 -> bf16 round-to-nearest-even
__device__ __forceinline__ unsigned short f2bf(float x) {
    union { float f; unsigned u; } v; v.f = x;
    unsigned r = v.u + 0x7FFFu + ((v.u >> 16) & 1u);
    return (unsigned short)(r >> 16);
}

__global__ __launch_bounds__(256) void causal_attn_kernel(
        const float* __restrict__ Qg, const float* __restrict__ Kg,
        const float* __restrict__ Vg, float* __restrict__ Og) {
    // K: row-major [64][256] bf16, XOR-swizzled (byte ^= (row&7)<<4)
    __shared__ unsigned short Ksh[KVBLK * DIM];
    // V^T: row-major [256][64] bf16 (row = V column), same XOR swizzle
    __shared__ unsigned short VshT[DIM * KVBLK];
    // P: per-wave [16][64] bf16, row stride 128B, XOR-swizzled
    __shared__ unsigned short Psh[4][16 * KVBLK];

    const int tid = threadIdx.x;
    const int w   = tid >> 6;      // wave 0..3
    const int l   = tid & 63;      // lane
    const int l15 = l & 15;
    const int lg  = l >> 4;        // lane group 0..3

    const int b     = blockIdx.x & 3;    // batch (pins batch to 2 XCDs)
    const int qt    = blockIdx.x >> 2;   // q tile 0..63
    const int qbase = qt * QBLK;

    // ---------- Q fragments in registers (16 rows/wave, scale 1/16 folded) ----------
    const int qrow = qbase + w * 16 + l15;
    const float* qp = Qg + (size_t)(b * S_LEN + qrow) * DIM + lg * 8;
    bf16x8 qf[8];
#pragma unroll
    for (int ks = 0; ks < 8; ++ks) {
        f32x4 a = *(const f32x4*)(qp + ks * 32);
        f32x4 c = *(const f32x4*)(qp + ks * 32 + 4);
        bf16x8 f;
        f[0] = (short)f2bf(a[0] * 0.0625f); f[1] = (short)f2bf(a[1] * 0.0625f);
        f[2] = (short)f2bf(a[2] * 0.0625f); f[3] = (short)f2bf(a[3] * 0.0625f);
        f[4] = (short)f2bf(c[0] * 0.0625f); f[5] = (short)f2bf(c[1] * 0.0625f);
        f[6] = (short)f2bf(c[2] * 0.0625f); f[7] = (short)f2bf(c[3] * 0.0625f);
        qf[ks] = f;
    }

    f32x4 acc[16];
#pragma unroll
    for (int i = 0; i < 16; ++i) acc[i] = (f32x4)0.0f;
    float mrun[4] = {-1e30f, -1e30f, -1e30f, -1e30f};
    float lrun[4] = {0.f, 0.f, 0.f, 0.f};

    const float* Kb = Kg + (size_t)b * S_LEN * DIM;
    const float* Vb = Vg + (size_t)b * S_LEN * DIM;

    for (int t = 0; t <= qt; ++t) {
        // ---------------- stage K tile (row-major, swizzled) ----------------
        {
            const float* src = Kb + (size_t)t * KVBLK * DIM;
#pragma unroll 4
            for (int it = 0; it < 16; ++it) {
                int row = 4 * it + w;          // wave reads one full row: coalesced
                int col = 4 * l;
                f32x4 x = *(const f32x4*)(src + row * DIM + col);
                u16x4 h;
                h.x = f2bf(x[0]); h.y = f2bf(x[1]); h.z = f2bf(x[2]); h.w = f2bf(x[3]);
                unsigned off = (unsigned)(row * 512 + col * 2);
                off ^= (unsigned)((row & 7) << 4);
                *(u16x4*)((char*)Ksh + off) = h;
            }
            // ------- stage V TRANSPOSED: VshT[col][row], col = tid -------
            const float* vs = Vb + (size_t)t * KVBLK * DIM;
#pragma unroll 4
            for (int g = 0; g < 16; ++g) {
                float x0 = vs[(4 * g + 0) * DIM + tid];   // coalesced across threads
                float x1 = vs[(4 * g + 1) * DIM + tid];
                float x2 = vs[(4 * g + 2) * DIM + tid];
                float x3 = vs[(4 * g + 3) * DIM + tid];
                u16x4 h;
                h.x = f2bf(x0); h.y = f2bf(x1); h.z = f2bf(x2); h.w = f2bf(x3);
                unsigned off = (unsigned)(tid * 128 + g * 8);
                off ^= (unsigned)((tid & 7) << 4);
                *(u16x4*)((char*)VshT + off) = h;
            }
        }
        __syncthreads();

        // ---------------- S = (Q*scale) K^T ----------------
        f32x4 sacc[4];
#pragma unroll
        for (int j = 0; j < 4; ++j) sacc[j] = (f32x4)0.0f;
#pragma unroll
        for (int ks = 0; ks < 8; ++ks) {
#pragma unroll
            for (int jt = 0; jt < 4; ++jt) {
                int j = jt * 16 + l15;
                unsigned off = (unsigned)(j * 512 + (ks * 32 + lg * 8) * 2);
                off ^= (unsigned)((j & 7) << 4);
                bf16x8 kb = *(const bf16x8*)((const char*)Ksh + off);
                sacc[jt] = __builtin_amdgcn_mfma_f32_16x16x32_bf16(qf[ks], kb, sacc[jt], 0, 0, 0);
            }
        }

        // ---------------- causal mask on diagonal tile (strict: j < i) ----------------
        if (t == qt) {
#pragma unroll
            for (int jt = 0; jt < 4; ++jt)
#pragma unroll
                for (int r = 0; r < 4; ++r) {
                    int jl = jt * 16 + l15;
                    int ml = w * 16 + lg * 4 + r;
                    if (jl >= ml) sacc[jt][r] = -3e38f;
                }
        }

        // ---------------- online softmax (rows live across 16 lanes) ----------------
        float pex[4][4];
        float corr[4];
#pragma unroll
        for (int r = 0; r < 4; ++r) {
            float mx = fmaxf(fmaxf(sacc[0][r], sacc[1][r]), fmaxf(sacc[2][r], sacc[3][r]));
            mx = fmaxf(mx, __shfl_xor(mx, 1));
            mx = fmaxf(mx, __shfl_xor(mx, 2));
            mx = fmaxf(mx, __shfl_xor(mx, 4));
            mx = fmaxf(mx, __shfl_xor(mx, 8));
            float mnew = fmaxf(mrun[r], mx);
            corr[r] = __expf(mrun[r] - mnew);
            mrun[r] = mnew;
            float s0 = __expf(sacc[0][r] - mnew);
            float s1 = __expf(sacc[1][r] - mnew);
            float s2 = __expf(sacc[2][r] - mnew);
            float s3 = __expf(sacc[3][r] - mnew);
            pex[0][r] = s0; pex[1][r] = s1; pex[2][r] = s2; pex[3][r] = s3;
            float ls = s0 + s1 + s2 + s3;
            ls += __shfl_xor(ls, 1);
            ls += __shfl_xor(ls, 2);
            ls += __shfl_xor(ls, 4);
            ls += __shfl_xor(ls, 8);
            lrun[r] = lrun[r] * corr[r] + ls;
        }
#pragma unroll
        for (int nt = 0; nt < 16; ++nt)
#pragma unroll
            for (int r = 0; r < 4; ++r) acc[nt][r] *= corr[r];

        // ---------------- P -> per-wave LDS (bf16, swizzled rows) ----------------
        {
            char* pw = (char*)&Psh[w][0];
#pragma unroll
            for (int jt = 0; jt < 4; ++jt)
#pragma unroll
                for (int r = 0; r < 4; ++r) {
                    int m = lg * 4 + r;
                    unsigned off = (unsigned)(m * 128 + (jt * 16 + l15) * 2);
                    off ^= (unsigned)((m & 7) << 4);
                    *(unsigned short*)(pw + off) = f2bf(pex[jt][r]);
                }
        }

        // ---------------- O += P V  (V^T rows, plain bf16x8 reads) ----------------
#pragma unroll
        for (int ks = 0; ks < 2; ++ks) {
            unsigned poff = (unsigned)(l15 * 128 + ks * 64 + lg * 16);
            poff ^= (unsigned)((l15 & 7) << 4);
            bf16x8 pa = *(const bf16x8*)((const char*)&Psh[w][0] + poff);
#pragma unroll
            for (int nt = 0; nt < 16; ++nt) {
                unsigned voff = (unsigned)((nt * 16 + l15) * 128 + ks * 64 + lg * 16);
                voff ^= (unsigned)((l15 & 7) << 4);
                bf16x8 vbf = *(const bf16x8*)((const char*)VshT + voff);
                acc[nt] = __builtin_amdgcn_mfma_f32_16x16x32_bf16(pa, vbf, acc[nt], 0, 0, 0);
            }
        }
        __syncthreads();
    }

    // ---------------- epilogue: normalize, write fp32 ----------------
    float rl[4];
#pragma unroll
    for (int r = 0; r < 4; ++r) rl[r] = (lrun[r] > 0.f) ? (1.0f / lrun[r]) : 0.f;
    float* ob = Og + (size_t)(b * S_LEN + qbase + w * 16) * DIM;
#pragma unroll
    for (int nt = 0; nt < 16; ++nt)
#pragma unroll
        for (int r = 0; r < 4; ++r) {
            int row = lg * 4 + r;
            ob[(size_t)row * DIM + nt * 16 + l15] = acc[nt][r] * rl[r];
        }
}

extern "C" void kernel_launch(void* const* d_in, const int* in_sizes, int n_in,
                              void* d_out, int out_size, void* d_ws, size_t ws_size,
                              hipStream_t stream) {
    const float* q = (const float*)d_in[0];
    const float* k = (const float*)d_in[1];
    const float* v = (const float*)d_in[2];
    float* o = (float*)d_out;
    dim3 grid(256), block(256);
    hipLaunchKernelGGL(causal_attn_kernel, grid, block, 0, stream, q, k, v, o);
}